// Round 13
// baseline (187.221 us; speedup 1.0000x reference)
//
#include <hip/hip_runtime.h>
#include <stdint.h>

// QuantizedLinear: out[N,OUT_F] = requant(int8gemm(x, W^T) + bias)
// x: [8192,4096] int8 (pushed int32), W: [4096,4096] int8 (pushed int32)
// out: int8 values stored as int32 (harness reads d_out as np.int32)
//
// r13: B bypasses LDS. Fragment-ordered panels let each wave load its B
// operands DIRECTLY from global (coalesced 1KB per global_load_dwordx4,
// already in MFMA lane layout). LDS traffic per tile drops 96+32 KB ->
// 64+16 KB (A only, 4x reuse). Schedule per tile t:
//   STAGE_A(t+2) -> LOADB(t+1) asm -> vmcnt(6) [A(t+1)+B(t) proven landed]
//   -> barrier -> READ8 A(t+1) asm -> lgkmcnt(8) [prev reads done]
//   -> 16 MFMA on tile t's registers.
// 4-slot A ring (64 KiB), 0 bank conflicts, 32x32x32 i8 MFMA, setprio,
// XCD-bijective swizzle.

#define M_DIM 8192
#define N_DIM 4096
#define K_DIM 4096
#define BM 256
#define BN 256
#define NKT2 (K_DIM / 32)            // 128 k-subtiles in panel layout
#define NBLK ((M_DIM / BM) * (N_DIM / BN))   // 512
#define ABUF (BM * 64)               // 16 KiB per A slot

using i32x4  = __attribute__((ext_vector_type(4))) int;
using i32x16 = __attribute__((ext_vector_type(16))) int;

typedef const __attribute__((address_space(1))) uint32_t* gptr_t;
typedef __attribute__((address_space(3))) uint32_t* lptr_t;

__device__ __forceinline__ void gload_lds16(const void* g, void* l) {
    __builtin_amdgcn_global_load_lds((gptr_t)g, (lptr_t)l, 16, 0, 0);
}

__device__ __forceinline__ int pack4(i32x4 v) {
    return (int)(((unsigned)v.x & 0xFFu) | (((unsigned)v.y & 0xFFu) << 8) |
                 (((unsigned)v.z & 0xFFu) << 16) | (((unsigned)v.w) << 24));
}

// int32 [rows][K_DIM] -> fragment-ordered panels [rows/32][NKT2][1024]
// block (rb,kt): byte[l*16+j] = (int8)src[rb*32 + (l&31)][kt*32 + (l>>5)*16 + j]
__global__ void pack_panels32_kernel(const int* __restrict__ src, int8_t* __restrict__ dst,
                                     int n_blocks) {
    int gid = blockIdx.x * blockDim.x + threadIdx.x;
    int blk = gid >> 6;
    int l = gid & 63;
    if (blk >= n_blocks) return;
    int rb = blk >> 7;               // / NKT2
    int kt = blk & (NKT2 - 1);
    const i32x4* s4 = (const i32x4*)(src + (size_t)(rb * 32 + (l & 31)) * K_DIM
                                         + kt * 32 + (l >> 5) * 16);
    i32x4 o;
    o.x = pack4(s4[0]); o.y = pack4(s4[1]); o.z = pack4(s4[2]); o.w = pack4(s4[3]);
    *(i32x4*)(dst + (size_t)blk * 1024 + l * 16) = o;
}

#define MFMA32(a, b, c) __builtin_amdgcn_mfma_i32_32x32x32_i8((a), (b), (c), 0, 0, 0)

// Inline-asm LDS read: compiler inserts NO automatic lgkm waits.
#define DSR(dst, base, off) \
    asm volatile("ds_read_b128 %0, %1 offset:%2" : "=&v"(dst) : "v"(base), "i"(off))

// Inline-asm global load direct to registers (B operands from panels).
#define GLB16(dst, addr, off) \
    asm volatile("global_load_dwordx4 %0, %1, off offset:%2" \
                 : "=&v"(dst) : "v"(addr), "i"(off))

// Issue 8 A prefetch reads for the k-tile in A slot at byte SOFF.
#define READ8(NS, SOFF)                                                         \
    DSR(fA[NS][0][0], aA, (SOFF) + 0);    DSR(fA[NS][0][1], aA, (SOFF) + 2048); \
    DSR(fA[NS][0][2], aA, (SOFF) + 4096); DSR(fA[NS][0][3], aA, (SOFF) + 6144); \
    DSR(fA[NS][1][0], aA, (SOFF) + 1024); DSR(fA[NS][1][1], aA, (SOFF) + 3072); \
    DSR(fA[NS][1][2], aA, (SOFF) + 5120); DSR(fA[NS][1][3], aA, (SOFF) + 7168);

// Load next tile's 4 B fragments (2 csubs x 2 ksubs) straight from panels.
#define LOADB(NS)                                                       \
    GLB16(fB[NS][0][0], Bg0, 0);    GLB16(fB[NS][1][0], Bg0, 1024);     \
    GLB16(fB[NS][0][1], Bg1, 0);    GLB16(fB[NS][1][1], Bg1, 1024);     \
    Bg0 += 2048; Bg1 += 2048;

// 8 independent MFMAs on set CS, k-half K.
#define MFMA_HALF(CS, K)                                                          \
    acc[0][0] = MFMA32(fA[CS][K][0], fB[CS][K][0], acc[0][0]);                    \
    acc[0][1] = MFMA32(fA[CS][K][0], fB[CS][K][1], acc[0][1]);                    \
    acc[1][0] = MFMA32(fA[CS][K][1], fB[CS][K][0], acc[1][0]);                    \
    acc[1][1] = MFMA32(fA[CS][K][1], fB[CS][K][1], acc[1][1]);                    \
    acc[2][0] = MFMA32(fA[CS][K][2], fB[CS][K][0], acc[2][0]);                    \
    acc[2][1] = MFMA32(fA[CS][K][2], fB[CS][K][1], acc[2][1]);                    \
    acc[3][0] = MFMA32(fA[CS][K][3], fB[CS][K][0], acc[3][0]);                    \
    acc[3][1] = MFMA32(fA[CS][K][3], fB[CS][K][1], acc[3][1]);

// Stage A of tile t+2 into slot (2 gload_lds/wave), advance pointer.
#define STAGE_A(SLOT)                                                   \
    gload_lds16(AgS,        ldsA + (SLOT) * ABUF + waoff);              \
    gload_lds16(AgS + 1024, ldsA + (SLOT) * ABUF + waoff + 1024);       \
    AgS += 2048;

// Steady-state tile t. vmcnt(6): allowed outstanding = this tile's
// 2 A-stages + 4 B-loads => A(t+1) (staged t-1) and B(t) (loaded t-1) landed.
#define TILE_FULL(SLOT_STG, SOFF_NXT, NS, CS)                           \
  { STAGE_A(SLOT_STG)                                                   \
    LOADB(NS)                                                           \
    asm volatile("s_waitcnt vmcnt(6)" ::: "memory");                    \
    __builtin_amdgcn_s_barrier();                                       \
    READ8(NS, SOFF_NXT)                                                 \
    asm volatile("s_waitcnt lgkmcnt(8)" ::: "memory");                  \
    __builtin_amdgcn_sched_barrier(0);                                  \
    __builtin_amdgcn_s_setprio(1);                                      \
    MFMA_HALF(CS, 0)                                                    \
    MFMA_HALF(CS, 1)                                                    \
    __builtin_amdgcn_s_setprio(0); }

__global__ __launch_bounds__(512, 2)
void qgemm32_kernel(const int8_t* __restrict__ xp, const int8_t* __restrict__ wp,
                    const int* __restrict__ bias, const float* __restrict__ wscale,
                    const float* __restrict__ iscale, const float* __restrict__ oscale,
                    const int* __restrict__ zp, int* __restrict__ out) {
    extern __shared__ int8_t lds[];
    int8_t* ldsA = lds;               // 4 slots * 16 KiB (A only)

    const int tid  = threadIdx.x;
    const int wave = tid >> 6;
    const int lane = tid & 63;

    // XCD-bijective swizzle (NBLK = 512, divisible by 8)
    int b = blockIdx.x;
    int s = (b & 7) * (NBLK >> 3) + (b >> 3);
    const int bcol = (s & 15) * BN;   // N_DIM/BN = 16
    const int brow = (s >> 4) * BM;

    const int wr = wave >> 2;         // 0..1  (M half, 128 rows = 4 rsubs)
    const int wc = wave & 3;          // 0..3  (N quarter, 64 cols = 2 csubs)

    // A staging source (fragment-ordered panels; advance 2048 B per K-tile)
    const int rb0 = brow >> 5;
    const int cb0 = bcol >> 5;
    const int8_t* AgS = xp + ((size_t)(rb0 + wave) * NKT2) * 1024 + lane * 16;
    const int waoff = wave * 2048;

    // B direct-load sources: csubs wc*2 and wc*2+1 (advance 2048 B per K-tile)
    const int8_t* Bg0 = wp + ((size_t)(cb0 + wc * 2)     * NKT2) * 1024 + lane * 16;
    const int8_t* Bg1 = wp + ((size_t)(cb0 + wc * 2 + 1) * NKT2) * 1024 + lane * 16;

    // asm ds_read base (low 32 bits of LDS pointer = DS addr)
    const unsigned aA = (unsigned)(uintptr_t)(ldsA + wr * 8192 + lane * 16);

    i32x16 acc[4][2] = {};
    i32x4 fA[2][2][4];                // [set][khalf][rsub] — all indices static
    i32x4 fB[2][2][2];                // [set][khalf][csub]

    // ---- prologue: stage A tile0->slot0, tile1->slot1; load B(0); drain ----
    STAGE_A(0)
    STAGE_A(1)
    LOADB(0)
    asm volatile("s_waitcnt vmcnt(0)" ::: "memory");
    __builtin_amdgcn_s_barrier();
    READ8(0, 0)                       // A(0) slot0 -> set0

    // ---- main loop: t = 0..59 in 15 groups of 4 ----
    // tile t: stage A slot (t+2)%4, load B(t+1) + read A slot (t+1)%4 into
    // set (t+1)%2, MFMA set t%2.
    for (int i = 0; i < 15; ++i) {
        TILE_FULL(2, 16384, 1, 0)     // t%4==0
        TILE_FULL(3, 32768, 0, 1)     // t%4==1
        TILE_FULL(0, 49152, 1, 0)     // t%4==2
        TILE_FULL(1,     0, 0, 1)     // t%4==3
    }
    // ---- t=60 (stage A62), t=61 (stage A63) ----
    TILE_FULL(2, 16384, 1, 0)
    TILE_FULL(3, 32768, 0, 1)
    // ---- t=62: no stage; load B(63); vmcnt(4) [only B(63) outstanding] ----
    {
        LOADB(1)
        asm volatile("s_waitcnt vmcnt(4)" ::: "memory");
        __builtin_amdgcn_s_barrier();
        READ8(1, 49152)
        asm volatile("s_waitcnt lgkmcnt(8)" ::: "memory");
        __builtin_amdgcn_sched_barrier(0);
        __builtin_amdgcn_s_setprio(1);
        MFMA_HALF(0, 0)
        MFMA_HALF(0, 1)
        __builtin_amdgcn_s_setprio(0);
    }
    // ---- t=63: final MFMA (set1); B(63) + last A reads must be done ----
    asm volatile("s_waitcnt vmcnt(0)" ::: "memory");
    asm volatile("s_waitcnt lgkmcnt(0)" ::: "memory");
    __builtin_amdgcn_sched_barrier(0);
    MFMA_HALF(1, 0)
    MFMA_HALF(1, 1)

    // ---- epilogue: out = clip(round((acc + bias) * (is*ws/os) + zp)) as int32 ----
    // 32x32 C/D layout (HW-verified): col = lane&31, row = (reg&3) + 8*(reg>>2) + 4*(lane>>5)
    const float is_v = iscale[0];
    const float os_v = oscale[0];
    const float zpf = (float)zp[0];
    #pragma unroll
    for (int c = 0; c < 2; c++) {
        int col = bcol + wc * 64 + c * 32 + (lane & 31);
        float sf = (is_v * wscale[col]) / os_v;
        int bz = bias[col];
        #pragma unroll
        for (int r = 0; r < 4; r++) {
            int rowb = brow + wr * 128 + r * 32 + 4 * (lane >> 5);
            #pragma unroll
            for (int reg = 0; reg < 16; reg++) {
                int row = rowb + (reg & 3) + 8 * (reg >> 2);
                float v = (float)(acc[r][c][reg] + bz) * sf + zpf;
                v = rintf(v);
                v = fminf(fmaxf(v, -128.0f), 127.0f);
                out[(size_t)row * N_DIM + col] = (int)v;
            }
        }
    }
}

#define MFMA_I8(a, b, c) __builtin_amdgcn_mfma_i32_16x16x64_i8((a), (b), (c), 0, 0, 0)

// Fallback (no workspace): direct int32 consumption, 128^2 tile (round-2 proven).
__global__ void qgemm_fallback(const int* __restrict__ x32, const int* __restrict__ w32,
                               const int* __restrict__ bias, const float* __restrict__ wscale,
                               const float* __restrict__ iscale, const float* __restrict__ oscale,
                               const int* __restrict__ zp, int* __restrict__ out) {
    __shared__ int8_t As[128][64];
    __shared__ int8_t Bs[128][64];
    const int tid  = threadIdx.x;
    const int wave = tid >> 6;
    const int lane = tid & 63;
    int b = blockIdx.x;
    int s = (b & 7) * (gridDim.x >> 3) + (b >> 3);
    const int bcol = (s & 31) * 128;
    const int brow = (s >> 5) * 128;
    const int wr = wave >> 1;
    const int wc = wave & 1;
    i32x4 acc[4][4] = {};
    for (int kt = 0; kt < K_DIM; kt += 64) {
        int row = tid >> 1;
        int h = tid & 1;
        const i32x4* sa = (const i32x4*)(x32 + (size_t)(brow + row) * K_DIM + kt + h * 32);
        const i32x4* sb = (const i32x4*)(w32 + (size_t)(bcol + row) * K_DIM + kt + h * 32);
        int pa[8], pb[8];
        #pragma unroll
        for (int j = 0; j < 8; j++) { pa[j] = pack4(sa[j]); pb[j] = pack4(sb[j]); }
        *(i32x4*)&As[row][h * 32]      = *(i32x4*)&pa[0];
        *(i32x4*)&As[row][h * 32 + 16] = *(i32x4*)&pa[4];
        *(i32x4*)&Bs[row][h * 32]      = *(i32x4*)&pb[0];
        *(i32x4*)&Bs[row][h * 32 + 16] = *(i32x4*)&pb[4];
        __syncthreads();
        i32x4 a_frag[4], b_frag[4];
        #pragma unroll
        for (int m = 0; m < 4; m++)
            a_frag[m] = *(const i32x4*)&As[wr * 64 + m * 16 + (lane & 15)][(lane >> 4) * 16];
        #pragma unroll
        for (int n = 0; n < 4; n++)
            b_frag[n] = *(const i32x4*)&Bs[wc * 64 + n * 16 + (lane & 15)][(lane >> 4) * 16];
        #pragma unroll
        for (int m = 0; m < 4; m++)
            #pragma unroll
            for (int n = 0; n < 4; n++)
                acc[m][n] = MFMA_I8(a_frag[m], b_frag[n], acc[m][n]);
        __syncthreads();
    }
    const float is_v = iscale[0];
    const float os_v = oscale[0];
    const float zpf = (float)zp[0];
    #pragma unroll
    for (int n = 0; n < 4; n++) {
        int col = bcol + wc * 64 + n * 16 + (lane & 15);
        float sf = (is_v * wscale[col]) / os_v;
        int bz = bias[col];
        #pragma unroll
        for (int m = 0; m < 4; m++) {
            int row0 = brow + wr * 64 + m * 16 + (lane >> 4) * 4;
            #pragma unroll
            for (int r = 0; r < 4; r++) {
                float v = (float)(acc[m][n][r] + bz) * sf + zpf;
                v = rintf(v);
                v = fminf(fmaxf(v, -128.0f), 127.0f);
                out[(size_t)(row0 + r) * N_DIM + col] = (int)v;
            }
        }
    }
}

extern "C" void kernel_launch(void* const* d_in, const int* in_sizes, int n_in,
                              void* d_out, int out_size, void* d_ws, size_t ws_size,
                              hipStream_t stream) {
    const int*   x32    = (const int*)d_in[0];
    const int*   w32    = (const int*)d_in[1];
    const int*   bias   = (const int*)d_in[2];
    const float* wscale = (const float*)d_in[3];
    const float* iscale = (const float*)d_in[4];
    const float* oscale = (const float*)d_in[5];
    const int*   zp     = (const int*)d_in[6];
    int* out = (int*)d_out;

    const size_t need = (size_t)M_DIM * K_DIM + (size_t)N_DIM * K_DIM;  // 50.3 MB
    const size_t lds_bytes = 4 * (size_t)ABUF;                          // 65536

    if (ws_size >= need) {
        int8_t* xp = (int8_t*)d_ws;
        int8_t* wp = xp + (size_t)M_DIM * K_DIM;
        const int nblkA = (M_DIM / 32) * NKT2;   // 32768
        const int nblkB = (N_DIM / 32) * NKT2;   // 16384
        pack_panels32_kernel<<<nblkA / 4, 256, 0, stream>>>(x32, xp, nblkA);
        pack_panels32_kernel<<<nblkB / 4, 256, 0, stream>>>(w32, wp, nblkB);
        (void)hipFuncSetAttribute((const void*)qgemm32_kernel,
                                  hipFuncAttributeMaxDynamicSharedMemorySize,
                                  (int)lds_bytes);
        qgemm32_kernel<<<NBLK, 512, lds_bytes, stream>>>(xp, wp, bias, wscale, iscale, oscale, zp, out);
    } else {
        qgemm_fallback<<<2048, 256, 0, stream>>>(x32, w32, bias, wscale, iscale, oscale, zp, out);
    }
}

// Round 14
// 183.925 us; speedup vs baseline: 1.0179x; 1.0179x over previous
//
#include <hip/hip_runtime.h>
#include <stdint.h>

// QuantizedLinear: out[N,OUT_F] = requant(int8gemm(x, W^T) + bias)
// x: [8192,4096] int8 (pushed int32), W: [4096,4096] int8 (pushed int32)
// out: int8 values stored as int32 (harness reads d_out as np.int32)
//
// r14: faithful port of the verified 256^2 8-phase template (m201) to i8.
// 4 phases per K-tile, each {ds_read A-pair (+B quad in ph0) || 1 gload_lds
// stage || barrier || 8 MFMA (setprio) || barrier}; 2 barriers/phase, fine
// ds_read||stage||MFMA interleave (the m196-measured lever). B frags live in
// regs across phases (each fragment read once). mfma_i32_16x16x64_i8,
// 16-row fragment-ordered panels (r5-verified), 4-slot ring + counted
// vmcnt(4) (r12-proven), XCD-bijective swizzle.

#define M_DIM 8192
#define N_DIM 4096
#define K_DIM 4096
#define BM 256
#define BN 256
#define NKT (K_DIM / 64)             // 64 k-tiles (1024B fragment blocks)
#define NBLK ((M_DIM / BM) * (N_DIM / BN))   // 512
#define ABUF (BM * 64)               // 16 KiB per slot (A or B)

using i32x4 = __attribute__((ext_vector_type(4))) int;

typedef const __attribute__((address_space(1))) uint32_t* gptr_t;
typedef __attribute__((address_space(3))) uint32_t* lptr_t;

__device__ __forceinline__ void gload_lds16(const void* g, void* l) {
    __builtin_amdgcn_global_load_lds((gptr_t)g, (lptr_t)l, 16, 0, 0);
}

__device__ __forceinline__ int pack4(i32x4 v) {
    return (int)(((unsigned)v.x & 0xFFu) | (((unsigned)v.y & 0xFFu) << 8) |
                 (((unsigned)v.z & 0xFFu) << 16) | (((unsigned)v.w) << 24));
}

// int32 [rows][K_DIM] -> fragment-ordered panels [rows/16][NKT][1024]
// block (rb,kt): byte[l*16+j] = (int8)src[rb*16 + (l&15)][kt*64 + (l>>4)*16 + j]
// (mfma_i32_16x16x64_i8 operand lane layout — HW-verified r2/r5)
__global__ void pack_panels16_kernel(const int* __restrict__ src, int8_t* __restrict__ dst,
                                     int n_blocks) {
    int gid = blockIdx.x * blockDim.x + threadIdx.x;
    int blk = gid >> 6;
    int l = gid & 63;
    if (blk >= n_blocks) return;
    int rb = blk >> 6;               // / NKT (=64)
    int kt = blk & (NKT - 1);
    const i32x4* s4 = (const i32x4*)(src + (size_t)(rb * 16 + (l & 15)) * K_DIM
                                         + kt * 64 + (l >> 4) * 16);
    i32x4 o;
    o.x = pack4(s4[0]); o.y = pack4(s4[1]); o.z = pack4(s4[2]); o.w = pack4(s4[3]);
    *(i32x4*)(dst + (size_t)blk * 1024 + l * 16) = o;
}

#define MF(a, b, c) __builtin_amdgcn_mfma_i32_16x16x64_i8((a), (b), (c), 0, 0, 0)

// Lane-linear fragment reads (bases include wave offset + lane*16; slot/frag
// offsets fold into ds_read offset immediates, max 56320 < 64K). 0 conflicts.
#define RD_A(S, m) (*(const i32x4*)(ArdB + (S) * 16384 + (m) * 1024))
#define RD_B(S, n) (*(const i32x4*)(BrdB + (S) * 16384 + (n) * 1024))

// Phase 0 of a tile: A frags 0,1 + ALL B frags; stage; barrier; 8 MFMA; barrier.
#define PH_FIRST(S, STG, TAIL)                                         \
  { i32x4 a0 = RD_A(S,0), a1 = RD_A(S,1);                              \
    b0 = RD_B(S,0); b1 = RD_B(S,1); b2 = RD_B(S,2); b3 = RD_B(S,3);    \
    STG;                                                               \
    __builtin_amdgcn_s_barrier();                                      \
    __builtin_amdgcn_s_setprio(1);                                     \
    acc[0][0]=MF(a0,b0,acc[0][0]); acc[0][1]=MF(a0,b1,acc[0][1]);      \
    acc[0][2]=MF(a0,b2,acc[0][2]); acc[0][3]=MF(a0,b3,acc[0][3]);      \
    acc[1][0]=MF(a1,b0,acc[1][0]); acc[1][1]=MF(a1,b1,acc[1][1]);      \
    acc[1][2]=MF(a1,b2,acc[1][2]); acc[1][3]=MF(a1,b3,acc[1][3]);      \
    __builtin_amdgcn_s_setprio(0);                                     \
    TAIL;                                                              \
    __builtin_amdgcn_s_barrier(); }

// Phases 1..3: A frags M0,M1; B from registers.
#define PH_NEXT(S, M0, M1, STG, TAIL)                                  \
  { i32x4 a0 = RD_A(S,M0), a1 = RD_A(S,M1);                            \
    STG;                                                               \
    __builtin_amdgcn_s_barrier();                                      \
    __builtin_amdgcn_s_setprio(1);                                     \
    acc[M0][0]=MF(a0,b0,acc[M0][0]); acc[M0][1]=MF(a0,b1,acc[M0][1]);  \
    acc[M0][2]=MF(a0,b2,acc[M0][2]); acc[M0][3]=MF(a0,b3,acc[M0][3]);  \
    acc[M1][0]=MF(a1,b0,acc[M1][0]); acc[M1][1]=MF(a1,b1,acc[M1][1]);  \
    acc[M1][2]=MF(a1,b2,acc[M1][2]); acc[M1][3]=MF(a1,b3,acc[M1][3]);  \
    __builtin_amdgcn_s_setprio(0);                                     \
    TAIL;                                                              \
    __builtin_amdgcn_s_barrier(); }

// One K-tile on slot S, staging next-next tile into slot SS (1 load/phase).
#define TILE_S(S, SS, TAIL)                                                            \
  PH_FIRST(S, { gload_lds16(AgS,  ldsA + (SS)*16384 + (2*wave)*1024);   AgS  += 1024; }, ((void)0)) \
  PH_NEXT(S, 2, 3, { gload_lds16(AgS2, ldsA + (SS)*16384 + (2*wave+1)*1024); AgS2 += 1024; }, ((void)0)) \
  PH_NEXT(S, 4, 5, { gload_lds16(BgS,  ldsB + (SS)*16384 + (2*wave)*1024);   BgS  += 1024; }, ((void)0)) \
  PH_NEXT(S, 6, 7, { gload_lds16(BgS2, ldsB + (SS)*16384 + (2*wave+1)*1024); BgS2 += 1024; }, TAIL)

#define TILE_N(S)                                 \
  PH_FIRST(S, ((void)0), ((void)0))               \
  PH_NEXT(S, 2, 3, ((void)0), ((void)0))          \
  PH_NEXT(S, 4, 5, ((void)0), ((void)0))          \
  PH_NEXT(S, 6, 7, ((void)0), ((void)0))

#define VM4 asm volatile("s_waitcnt vmcnt(4)" ::: "memory")
#define VM0 asm volatile("s_waitcnt vmcnt(0)" ::: "memory")

// Prologue staging: all 4 subtile-loads of one tile into slot S.
#define STAGE_ALL(S)                                                   \
  gload_lds16(AgS,  ldsA + (S)*16384 + (2*wave)*1024);   AgS  += 1024; \
  gload_lds16(AgS2, ldsA + (S)*16384 + (2*wave+1)*1024); AgS2 += 1024; \
  gload_lds16(BgS,  ldsB + (S)*16384 + (2*wave)*1024);   BgS  += 1024; \
  gload_lds16(BgS2, ldsB + (S)*16384 + (2*wave+1)*1024); BgS2 += 1024;

__global__ __launch_bounds__(512, 2)
void qgemm16_kernel(const int8_t* __restrict__ xp, const int8_t* __restrict__ wp,
                    const int* __restrict__ bias, const float* __restrict__ wscale,
                    const float* __restrict__ iscale, const float* __restrict__ oscale,
                    const int* __restrict__ zp, int* __restrict__ out) {
    extern __shared__ int8_t lds[];
    int8_t* ldsA = lds;               // 4 slots * 16 KiB, [m-subtile 0..15][1024]
    int8_t* ldsB = lds + 4 * ABUF;    // 4 slots * 16 KiB, [n-subtile 0..15][1024]

    const int tid  = threadIdx.x;
    const int wave = tid >> 6;
    const int lane = tid & 63;

    // XCD-bijective swizzle (NBLK = 512, divisible by 8)
    int b = blockIdx.x;
    int s = (b & 7) * (NBLK >> 3) + (b >> 3);
    const int bcol = (s & 15) * BN;   // N_DIM/BN = 16
    const int brow = (s >> 4) * BM;

    const int wr = wave >> 2;         // 0..1  (M half: subtiles wr*8..wr*8+7)
    const int wc = wave & 3;          // 0..3  (N quarter: subtiles wc*4..wc*4+3)

    // staging sources: wave stages A subtiles 2w,2w+1 and B subtiles 2w,2w+1
    // (panel addr of subtile u, k-tile t: base + (u*NKT + t)*1024 + lane*16)
    const int rb0 = brow >> 4;        // 16 m-subtiles per tile
    const int cb0 = bcol >> 4;
    const int8_t* AgS  = xp + ((size_t)(rb0 + 2 * wave)     * NKT) * 1024 + lane * 16;
    const int8_t* AgS2 = xp + ((size_t)(rb0 + 2 * wave + 1) * NKT) * 1024 + lane * 16;
    const int8_t* BgS  = wp + ((size_t)(cb0 + 2 * wave)     * NKT) * 1024 + lane * 16;
    const int8_t* BgS2 = wp + ((size_t)(cb0 + 2 * wave + 1) * NKT) * 1024 + lane * 16;

    // fragment read bases
    const int8_t* ArdB = ldsA + (wr * 8) * 1024 + lane * 16;
    const int8_t* BrdB = ldsB + (wc * 4) * 1024 + lane * 16;

    i32x4 acc[8][4] = {};
    i32x4 b0, b1, b2, b3;

    // ---- prologue: stage tile0->slot0, tile1->slot1; land tile0 ----
    STAGE_ALL(0)
    STAGE_ALL(1)
    VM4;                              // tile0's 4 landed; tile1's in flight
    __builtin_amdgcn_s_barrier();

    // ---- main loop: t = 0..59 in 15 groups of 4; tile t reads slot t%4,
    //      stages tile t+2 into slot (t+2)%4, tail vmcnt(4) ----
    for (int i = 0; i < 15; ++i) {
        TILE_S(0, 2, VM4)
        TILE_S(1, 3, VM4)
        TILE_S(2, 0, VM4)
        TILE_S(3, 1, VM4)
    }
    // ---- t=60 (stage 62->slot2), t=61 (stage 63->slot3, drain all) ----
    TILE_S(0, 2, VM4)
    TILE_S(1, 3, VM0)
    // ---- t=62, t=63: no staging ----
    TILE_N(2)
    TILE_N(3)

    // ---- epilogue: out = clip(round((acc + bias) * (is*ws/os) + zp)) as int32 ----
    // 16x16 C/D layout (HW-verified r2/r5): col=lane&15, row=(lane>>4)*4+r
    const float is_v = iscale[0];
    const float os_v = oscale[0];
    const float zpf = (float)zp[0];
    #pragma unroll
    for (int n = 0; n < 4; n++) {
        int col = bcol + wc * 64 + n * 16 + (lane & 15);
        float sf = (is_v * wscale[col]) / os_v;
        int bz = bias[col];
        #pragma unroll
        for (int m = 0; m < 8; m++) {
            int row0 = brow + wr * 128 + m * 16 + (lane >> 4) * 4;
            #pragma unroll
            for (int r = 0; r < 4; r++) {
                float v = (float)(acc[m][n][r] + bz) * sf + zpf;
                v = rintf(v);
                v = fminf(fmaxf(v, -128.0f), 127.0f);
                out[(size_t)(row0 + r) * N_DIM + col] = (int)v;
            }
        }
    }
}

#define MFMA_I8(a, b, c) __builtin_amdgcn_mfma_i32_16x16x64_i8((a), (b), (c), 0, 0, 0)

// Fallback (no workspace): direct int32 consumption, 128^2 tile (round-2 proven).
__global__ void qgemm_fallback(const int* __restrict__ x32, const int* __restrict__ w32,
                               const int* __restrict__ bias, const float* __restrict__ wscale,
                               const float* __restrict__ iscale, const float* __restrict__ oscale,
                               const int* __restrict__ zp, int* __restrict__ out) {
    __shared__ int8_t As[128][64];
    __shared__ int8_t Bs[128][64];
    const int tid  = threadIdx.x;
    const int wave = tid >> 6;
    const int lane = tid & 63;
    int b = blockIdx.x;
    int s = (b & 7) * (gridDim.x >> 3) + (b >> 3);
    const int bcol = (s & 31) * 128;
    const int brow = (s >> 5) * 128;
    const int wr = wave >> 1;
    const int wc = wave & 1;
    i32x4 acc[4][4] = {};
    for (int kt = 0; kt < K_DIM; kt += 64) {
        int row = tid >> 1;
        int h = tid & 1;
        const i32x4* sa = (const i32x4*)(x32 + (size_t)(brow + row) * K_DIM + kt + h * 32);
        const i32x4* sb = (const i32x4*)(w32 + (size_t)(bcol + row) * K_DIM + kt + h * 32);
        int pa[8], pb[8];
        #pragma unroll
        for (int j = 0; j < 8; j++) { pa[j] = pack4(sa[j]); pb[j] = pack4(sb[j]); }
        *(i32x4*)&As[row][h * 32]      = *(i32x4*)&pa[0];
        *(i32x4*)&As[row][h * 32 + 16] = *(i32x4*)&pa[4];
        *(i32x4*)&Bs[row][h * 32]      = *(i32x4*)&pb[0];
        *(i32x4*)&Bs[row][h * 32 + 16] = *(i32x4*)&pb[4];
        __syncthreads();
        i32x4 a_frag[4], b_frag[4];
        #pragma unroll
        for (int m = 0; m < 4; m++)
            a_frag[m] = *(const i32x4*)&As[wr * 64 + m * 16 + (lane & 15)][(lane >> 4) * 16];
        #pragma unroll
        for (int n = 0; n < 4; n++)
            b_frag[n] = *(const i32x4*)&Bs[wc * 64 + n * 16 + (lane & 15)][(lane >> 4) * 16];
        #pragma unroll
        for (int m = 0; m < 4; m++)
            #pragma unroll
            for (int n = 0; n < 4; n++)
                acc[m][n] = MFMA_I8(a_frag[m], b_frag[n], acc[m][n]);
        __syncthreads();
    }
    const float is_v = iscale[0];
    const float os_v = oscale[0];
    const float zpf = (float)zp[0];
    #pragma unroll
    for (int n = 0; n < 4; n++) {
        int col = bcol + wc * 64 + n * 16 + (lane & 15);
        float sf = (is_v * wscale[col]) / os_v;
        int bz = bias[col];
        #pragma unroll
        for (int m = 0; m < 4; m++) {
            int row0 = brow + wr * 64 + m * 16 + (lane >> 4) * 4;
            #pragma unroll
            for (int r = 0; r < 4; r++) {
                float v = (float)(acc[m][n][r] + bz) * sf + zpf;
                v = rintf(v);
                v = fminf(fmaxf(v, -128.0f), 127.0f);
                out[(size_t)(row0 + r) * N_DIM + col] = (int)v;
            }
        }
    }
}

extern "C" void kernel_launch(void* const* d_in, const int* in_sizes, int n_in,
                              void* d_out, int out_size, void* d_ws, size_t ws_size,
                              hipStream_t stream) {
    const int*   x32    = (const int*)d_in[0];
    const int*   w32    = (const int*)d_in[1];
    const int*   bias   = (const int*)d_in[2];
    const float* wscale = (const float*)d_in[3];
    const float* iscale = (const float*)d_in[4];
    const float* oscale = (const float*)d_in[5];
    const int*   zp     = (const int*)d_in[6];
    int* out = (int*)d_out;

    const size_t need = (size_t)M_DIM * K_DIM + (size_t)N_DIM * K_DIM;  // 50.3 MB
    const size_t lds_bytes = 8 * (size_t)ABUF;                          // 131072

    if (ws_size >= need) {
        int8_t* xp = (int8_t*)d_ws;
        int8_t* wp = xp + (size_t)M_DIM * K_DIM;
        const int nblkA = (M_DIM / 16) * NKT;   // 32768
        const int nblkB = (N_DIM / 16) * NKT;   // 16384
        pack_panels16_kernel<<<nblkA / 4, 256, 0, stream>>>(x32, xp, nblkA);
        pack_panels16_kernel<<<nblkB / 4, 256, 0, stream>>>(w32, wp, nblkB);
        (void)hipFuncSetAttribute((const void*)qgemm16_kernel,
                                  hipFuncAttributeMaxDynamicSharedMemorySize,
                                  (int)lds_bytes);
        qgemm16_kernel<<<NBLK, 512, lds_bytes, stream>>>(xp, wp, bias, wscale, iscale, oscale, zp, out);
    } else {
        qgemm_fallback<<<2048, 256, 0, stream>>>(x32, w32, bias, wscale, iscale, oscale, zp, out);
    }
}